// Round 2
// baseline (35447.345 us; speedup 1.0000x reference)
//
#include <hip/hip_runtime.h>

#define T_N 4096
#define B_N 64
#define D_N 128

typedef _Float16 f16;
typedef _Float16 f16x4 __attribute__((ext_vector_type(4)));
typedef _Float16 f16x8 __attribute__((ext_vector_type(8)));
typedef float f32x16 __attribute__((ext_vector_type(16)));
typedef unsigned int u32;

__device__ __forceinline__ f16x8 cat8(f16x4 a, f16x4 b) {
  return __builtin_shufflevector(a, b, 0, 1, 2, 3, 4, 5, 6, 7);
}
__device__ __forceinline__ u32 pk2(f16 a, f16 b) {
  union { f16 x[2]; u32 u; } z;
  z.x[0] = a; z.x[1] = b;
  return z.u;
}
__device__ __forceinline__ u32 sx32(u32 v) {
  return (u32)__shfl_xor((int)v, 32, 64);
}
// Build a B-operand fragment from per-lane packed pairs.
// Element e on half h must hold k-offset (8h+e) within the 16-wide window:
// h==0 -> [own quad s | partner quad s] ; h==1 -> [partner quad s+1 | own quad s+1]
__device__ __forceinline__ f16x8 bfrag(int h, u32 qs0, u32 qs1, u32 qt0, u32 qt1) {
  u32 o0 = h ? qt0 : qs0;
  u32 o1 = h ? qt1 : qs1;
  u32 d0 = h ? qs0 : qt0;
  u32 d1 = h ? qs1 : qt1;
  u32 r0 = sx32(d0), r1 = sx32(d1);
  union { u32 u[4]; f16x8 v; } z;
  z.u[0] = h ? r0 : o0;
  z.u[1] = h ? r1 : o1;
  z.u[2] = h ? o0 : r0;
  z.u[3] = h ? o1 : r1;
  return z.v;
}

// Sequential RLS scan: 1 workgroup, 4 waves, scaled covariance Pt = FF^t * P
// resident in MFMA accumulators (stays O(100) -> f16-safe forever).
__global__ __launch_bounds__(256, 1) void rls_seq(
    const float* __restrict__ xg, const float* __restrict__ tg,
    float* __restrict__ attn) {
  constexpr float FF = 0.99f, EPS = 1e-8f;
  constexpr float FEPS = FF + EPS;
  constexpr float INVB = 1.0f / 64.0f;

  // strides chosen so (u32_stride mod 4)==2 -> <=4-way LDS bank conflicts
  __shared__ alignas(16) f16 X16[64][132];    // x16[b][j]
  __shared__ alignas(16) f16 Xt16[128][68];   // x16[b][j] stored [j][b]
  __shared__ float theta[128];
  __shared__ alignas(16) float pairs[4][64][2];   // per-wave (q, ypred) partials
  __shared__ alignas(16) float rden_err[64][2];   // (rd, err) per b

  const int tid = threadIdx.x;
  const int w = tid >> 6;        // wave id = owned i-column tile
  const int lane = tid & 63;
  const int l31 = lane & 31;
  const int h = lane >> 5;
  const int i32 = 32 * w + l31;  // this lane's P/K column index i

  // Pacc tile jm, element r  <->  Pt[i32][j], j = 32*jm + (r&3) + 8*(r>>2) + 4*h
  f32x16 Pacc[4];
#pragma unroll
  for (int jm = 0; jm < 4; ++jm)
#pragma unroll
    for (int r = 0; r < 16; ++r) {
      const int j = 32 * jm + (r & 3) + 8 * (r >> 2) + 4 * h;
      Pacc[jm][r] = (j == i32) ? 100.0f : 0.0f;  // P0 = I/lambda, ft0 = 1
    }
  if (tid < 128) theta[tid] = 0.0f;

  // x prefetch mapping: thread covers rows (2p, 2p+1), cols 16*jbk..16*jbk+15
  const int p = l31;
  const int jbk = 2 * w + h;
  const long rstride = (long)T_N * D_N;
  const float* xrow0 = xg + (long)(2 * p) * rstride + 16 * jbk;

  float4 xr[8];
  float tcur = 0.0f, tnxt = 0.0f;
  float ft = 1.0f;  // FF^t

#define XLOAD(tt)                                                     \
  {                                                                   \
    _Pragma("unroll") for (int q = 0; q < 4; ++q) {                   \
      xr[q] = *(const float4*)(xrow0 + (long)(tt)*D_N + 4 * q);       \
      xr[4 + q] = *(const float4*)(xrow0 + rstride + (long)(tt)*D_N + 4 * q); \
    }                                                                 \
  }

#define XPREP()                                                       \
  {                                                                   \
    f16 c0[16], c1[16];                                               \
    _Pragma("unroll") for (int q = 0; q < 4; ++q) {                   \
      const float* f0 = (const float*)&xr[q];                         \
      const float* f1 = (const float*)&xr[4 + q];                     \
      _Pragma("unroll") for (int e = 0; e < 4; ++e) {                 \
        c0[4 * q + e] = (f16)f0[e];                                   \
        c1[4 * q + e] = (f16)f1[e];                                   \
      }                                                               \
    }                                                                 \
    _Pragma("unroll") for (int q = 0; q < 4; ++q) {                   \
      f16x4 v0 = {c0[4 * q], c0[4 * q + 1], c0[4 * q + 2], c0[4 * q + 3]}; \
      f16x4 v1 = {c1[4 * q], c1[4 * q + 1], c1[4 * q + 2], c1[4 * q + 3]}; \
      *(f16x4*)&X16[2 * p][16 * jbk + 4 * q] = v0;                    \
      *(f16x4*)&X16[2 * p + 1][16 * jbk + 4 * q] = v1;                \
    }                                                                 \
    _Pragma("unroll") for (int c = 0; c < 16; ++c) {                  \
      *(u32*)&Xt16[16 * jbk + c][2 * p] = pk2(c0[c], c1[c]);          \
    }                                                                 \
  }

  // prologue: stage x(0), tgt(0)
  XLOAD(0);
  if (tid < B_N) tcur = tg[(long)tid * T_N];
  XPREP();
  __syncthreads();

  for (int t = 0; t < T_N; ++t) {
    // ---- (A) issue prefetch of x(t+1), tgt(t+1)
    if (t + 1 < T_N) {
      XLOAD(t + 1);
      if (tid < B_N) tnxt = tg[(long)tid * T_N + (t + 1)];
    }

    // ---- (B) pack Pt (fp32 regs) into f16 hi/lo pair quads
    u32 pqh[4][4][2], pql[4][4][2];
#pragma unroll
    for (int jm = 0; jm < 4; ++jm)
#pragma unroll
      for (int rq = 0; rq < 4; ++rq) {
        f16 hi[4], lo[4];
#pragma unroll
        for (int c = 0; c < 4; ++c) {
          const float v = Pacc[jm][4 * rq + c];
          hi[c] = (f16)v;
          lo[c] = (f16)(v - (float)hi[c]);
        }
        pqh[jm][rq][0] = pk2(hi[0], hi[1]);
        pqh[jm][rq][1] = pk2(hi[2], hi[3]);
        pql[jm][rq][0] = pk2(lo[0], lo[1]);
        pql[jm][rq][1] = pk2(lo[2], lo[3]);
      }

    // ---- (C) m1: Ptx = X * Pt^T   (out rows b, cols i = wave's 32 columns)
    f32x16 acc1[2];
#pragma unroll
    for (int r = 0; r < 16; ++r) { acc1[0][r] = 0.0f; acc1[1][r] = 0.0f; }
#pragma unroll
    for (int ks = 0; ks < 8; ++ks) {
      const int a = ks >> 1, s = 2 * (ks & 1);
      f16x8 bh = bfrag(h, pqh[a][s][0], pqh[a][s][1], pqh[a][s + 1][0], pqh[a][s + 1][1]);
      f16x8 bl = bfrag(h, pql[a][s][0], pql[a][s][1], pql[a][s + 1][0], pql[a][s + 1][1]);
      const int j0 = 16 * ks + 8 * h;
      f16x8 a0 = cat8(*(const f16x4*)&X16[l31][j0], *(const f16x4*)&X16[l31][j0 + 4]);
      f16x8 a1 = cat8(*(const f16x4*)&X16[32 + l31][j0], *(const f16x4*)&X16[32 + l31][j0 + 4]);
      acc1[0] = __builtin_amdgcn_mfma_f32_32x32x16_f16(a0, bh, acc1[0], 0, 0, 0);
      acc1[0] = __builtin_amdgcn_mfma_f32_32x32x16_f16(a0, bl, acc1[0], 0, 0, 0);
      acc1[1] = __builtin_amdgcn_mfma_f32_32x32x16_f16(a1, bh, acc1[1], 0, 0, 0);
      acc1[1] = __builtin_amdgcn_mfma_f32_32x32x16_f16(a1, bl, acc1[1], 0, 0, 0);
    }

    // ---- (D) q & y_pred partials: per lane fixed i, butterfly over i
    const float th = theta[i32];
#pragma unroll
    for (int bm = 0; bm < 2; ++bm)
#pragma unroll
      for (int rq = 0; rq < 4; ++rq) {
        const int b0 = 32 * bm + 8 * rq + 4 * h;
        const f16x4 xq = *(const f16x4*)&Xt16[i32][b0];
        float dv[4], yv[4];
#pragma unroll
        for (int c = 0; c < 4; ++c) {
          const float xf = (float)xq[c];
          dv[c] = xf * acc1[bm][4 * rq + c];  // x * Ptx
          yv[c] = xf * th;                    // x * theta
        }
#pragma unroll
        for (int m = 1; m <= 16; m <<= 1)
#pragma unroll
          for (int c = 0; c < 4; ++c) {
            dv[c] += __shfl_xor(dv[c], m, 64);
            yv[c] += __shfl_xor(yv[c], m, 64);
          }
        if (l31 == 0) {  // lanes 0 and 32 hold sums over this wave's 32 i
          float4 w0 = {dv[0], yv[0], dv[1], yv[1]};
          float4 w1 = {dv[2], yv[2], dv[3], yv[3]};
          *(float4*)&pairs[w][b0][0] = w0;
          *(float4*)&pairs[w][b0 + 2][0] = w1;
        }
      }
    __syncthreads();

    // ---- (E) finalize per-b scalars, emit raw attention
    // true denom = FF + EPS + x'Px = (q + FEPS*ft)/ft ; K = Ptx * rd
    if (tid < B_N) {
      const float qs = pairs[0][tid][0] + pairs[1][tid][0] + pairs[2][tid][0] + pairs[3][tid][0];
      const float ys = pairs[0][tid][1] + pairs[1][tid][1] + pairs[2][tid][1] + pairs[3][tid][1];
      const float rd = 1.0f / (qs + FEPS * ft);
      rden_err[tid][0] = rd;
      rden_err[tid][1] = tcur - ys;
      attn[(long)tid * T_N + t] = ys;
    }
    __syncthreads();

    // ---- (F) K = Ptx*rd (regs), theta update, pack km = -ft*K/B (hi/lo)
    const float negsc = -ft * INVB;
    u32 kqh[2][4][2], kql[2][4][2];
    float tsum = 0.0f;
#pragma unroll
    for (int bm = 0; bm < 2; ++bm)
#pragma unroll
      for (int rq = 0; rq < 4; ++rq) {
        const int b0 = 32 * bm + 8 * rq + 4 * h;
        const float4 q0 = *(const float4*)&rden_err[b0][0];      // rd0,e0,rd1,e1
        const float4 q1 = *(const float4*)&rden_err[b0 + 2][0];  // rd2,e2,rd3,e3
        float kr[4];
        kr[0] = acc1[bm][4 * rq + 0] * q0.x;
        kr[1] = acc1[bm][4 * rq + 1] * q0.z;
        kr[2] = acc1[bm][4 * rq + 2] * q1.x;
        kr[3] = acc1[bm][4 * rq + 3] * q1.z;
        tsum += kr[0] * q0.y + kr[1] * q0.w + kr[2] * q1.y + kr[3] * q1.w;
        f16 hi[4], lo[4];
#pragma unroll
        for (int c = 0; c < 4; ++c) {
          const float km = kr[c] * negsc;
          hi[c] = (f16)km;
          lo[c] = (f16)(km - (float)hi[c]);
        }
        kqh[bm][rq][0] = pk2(hi[0], hi[1]);
        kqh[bm][rq][1] = pk2(hi[2], hi[3]);
        kql[bm][rq][0] = pk2(lo[0], lo[1]);
        kql[bm][rq][1] = pk2(lo[2], lo[3]);
      }
    tsum += __shfl_xor(tsum, 32, 64);
    if (h == 0) theta[i32] += tsum * INVB;  // theta += mean_b(K*err)

    // ---- (G) m2: Pt_{t+1} = Pt - ft * mean_b(K x^T)   (no 1/FF: folded into ft)
#pragma unroll
    for (int ks = 0; ks < 4; ++ks) {
      const int a = ks >> 1, s = 2 * (ks & 1);
      f16x8 bh = bfrag(h, kqh[a][s][0], kqh[a][s][1], kqh[a][s + 1][0], kqh[a][s + 1][1]);
      f16x8 bl = bfrag(h, kql[a][s][0], kql[a][s][1], kql[a][s + 1][0], kql[a][s + 1][1]);
      const int b0 = 16 * ks + 8 * h;
#pragma unroll
      for (int jm = 0; jm < 4; ++jm) {
        f16x8 a2 = cat8(*(const f16x4*)&Xt16[32 * jm + l31][b0],
                        *(const f16x4*)&Xt16[32 * jm + l31][b0 + 4]);
        Pacc[jm] = __builtin_amdgcn_mfma_f32_32x32x16_f16(a2, bh, Pacc[jm], 0, 0, 0);
        Pacc[jm] = __builtin_amdgcn_mfma_f32_32x32x16_f16(a2, bl, Pacc[jm], 0, 0, 0);
      }
    }
    __syncthreads();

    // ---- (I) stage x(t+1) into LDS (after all reads of step-t X)
    if (t + 1 < T_N) {
      XPREP();
      tcur = tnxt;
    }
    __syncthreads();
    ft *= FF;
  }
#undef XLOAD
#undef XPREP
}

// softmax over time per batch row (in place on raw attn)
__global__ void softmax_k(float* __restrict__ attn) {
  const int b = blockIdx.x;
  float* row = attn + (long)b * T_N;
  __shared__ float sv[T_N];
  __shared__ float red[256];
  const int tid = threadIdx.x;
  float m = -1e30f;
  for (int k = tid; k < T_N; k += 256) {
    const float v = row[k];
    sv[k] = v;
    m = fmaxf(m, v);
  }
  red[tid] = m;
  __syncthreads();
  for (int off = 128; off > 0; off >>= 1) {
    if (tid < off) red[tid] = fmaxf(red[tid], red[tid + off]);
    __syncthreads();
  }
  const float M = red[0];
  __syncthreads();
  float s = 0.0f;
  for (int k = tid; k < T_N; k += 256) {
    const float e = __expf(sv[k] - M);
    sv[k] = e;
    s += e;
  }
  red[tid] = s;
  __syncthreads();
  for (int off = 128; off > 0; off >>= 1) {
    if (tid < off) red[tid] += red[tid + off];
    __syncthreads();
  }
  const float inv = 1.0f / red[0];
  for (int k = tid; k < T_N; k += 256) row[k] = sv[k] * inv;
}

// out[b][d] = sum_t x[b][t][d] * attn_norm[b][t]
__global__ void einsum_k(const float* __restrict__ xg,
                         const float* __restrict__ attn,
                         float* __restrict__ out) {
  const int b = blockIdx.x;
  const int d = threadIdx.x;  // 128 threads
  __shared__ float as[T_N];
  for (int k = d; k < T_N; k += 128) as[k] = attn[(long)b * T_N + k];
  __syncthreads();
  const float* xb = xg + (long)b * T_N * D_N + d;
  float acc = 0.0f;
#pragma unroll 4
  for (int t = 0; t < T_N; ++t) acc += xb[(long)t * D_N] * as[t];
  out[b * D_N + d] = acc;
}

extern "C" void kernel_launch(void* const* d_in, const int* in_sizes, int n_in,
                              void* d_out, int out_size, void* d_ws, size_t ws_size,
                              hipStream_t stream) {
  const float* x = (const float*)d_in[0];
  const float* tgt = (const float*)d_in[1];
  float* out = (float*)d_out;
  float* attn = out + B_N * D_N;  // outputs: [output (B,D) | attn_norm (B,T)]

  rls_seq<<<dim3(1), dim3(256), 0, stream>>>(x, tgt, attn);
  softmax_k<<<dim3(B_N), dim3(256), 0, stream>>>(attn);
  einsum_k<<<dim3(B_N), dim3(128), 0, stream>>>(x, attn, out);
}

// Round 5
// 18472.910 us; speedup vs baseline: 1.9189x; 1.9189x over previous
//
#include <hip/hip_runtime.h>

#define T_N 4096
#define B_N 64
#define D_N 128

typedef _Float16 f16;
typedef _Float16 f16x4 __attribute__((ext_vector_type(4)));
typedef _Float16 f16x8 __attribute__((ext_vector_type(8)));
typedef __fp16 fp16x2 __attribute__((ext_vector_type(2)));
typedef float f32x16 __attribute__((ext_vector_type(16)));
typedef unsigned int u32;
typedef unsigned int u32x2 __attribute__((ext_vector_type(2)));

__device__ __forceinline__ f16x8 cat8(f16x4 a, f16x4 b) {
  return __builtin_shufflevector(a, b, 0, 1, 2, 3, 4, 5, 6, 7);
}
__device__ __forceinline__ u32 pk2(f16 a, f16 b) {
  union { f16 x[2]; u32 u; } z;
  z.x[0] = a; z.x[1] = b;
  return z.u;
}
__device__ __forceinline__ u32 pkrtz(float a, float b) {
  union { fp16x2 h; u32 u; } z;
  z.h = __builtin_amdgcn_cvt_pkrtz(a, b);
  return z.u;
}
__device__ __forceinline__ u32 sx32(u32 v) {
  return (u32)__shfl_xor((int)v, 32, 64);
}
__device__ __forceinline__ float sx32f(float v) {
  return __shfl_xor(v, 32, 64);
}

// raw barrier: LDS-visibility only; does NOT drain vmcnt (prefetch stays in flight)
__device__ __forceinline__ void wg_barrier() {
  asm volatile("s_waitcnt lgkmcnt(0)" ::: "memory");
  __builtin_amdgcn_sched_barrier(0);
  __builtin_amdgcn_s_barrier();
  __builtin_amdgcn_sched_barrier(0);
}

// B/A fragment builder: element e at lane (l31,h) = quad-data for k-offset 8h+e
// within a 16-wide k-window. qs = quad rq=s (k%8 in 0..3 at h=0), qt = quad rq=s+1.
__device__ __forceinline__ f16x8 bfrag(int h, u32 qs0, u32 qs1, u32 qt0, u32 qt1) {
#if __has_builtin(__builtin_amdgcn_permlane32_swap)
  u32x2 s0 = __builtin_amdgcn_permlane32_swap(qs0, qt0, false, false);
  u32x2 s1 = __builtin_amdgcn_permlane32_swap(qs1, qt1, false, false);
  union { u32 u[4]; f16x8 v; } z;
  z.u[0] = s0[0]; z.u[1] = s1[0]; z.u[2] = s0[1]; z.u[3] = s1[1];
  return z.v;
#else
  u32 o0 = h ? qt0 : qs0;
  u32 o1 = h ? qt1 : qs1;
  u32 d0 = h ? qs0 : qt0;
  u32 d1 = h ? qs1 : qt1;
  u32 r0 = sx32(d0), r1 = sx32(d1);
  union { u32 u[4]; f16x8 v; } z;
  z.u[0] = h ? r0 : o0;
  z.u[1] = h ? r1 : o1;
  z.u[2] = h ? o0 : r0;
  z.u[3] = h ? o1 : r1;
  return z.v;
#endif
}

// Sequential RLS scan: 1 workgroup, 4 waves, scaled covariance Pt = FF^t * P
// resident in MFMA accumulators. m1 (X*Pt^T) hi+lo, m1' (Pt*X^T, for denom/ypred)
// hi-only, m2 (P update) hi-only (km underflows f16 past t~800 anyway; tail
// updates are < 1e-6 relative of Pt).
__global__ __launch_bounds__(256, 1) void rls_seq(
    const float* __restrict__ xg, const float* __restrict__ tg,
    float* __restrict__ attn) {
  constexpr float FF = 0.99f, EPS = 1e-8f;
  constexpr float FEPS = FF + EPS;
  constexpr float INVB = 1.0f / 64.0f;

  // double-buffered X tiles; u32-strides mod 4 == 2 -> 2-way (free) bank aliasing
  __shared__ alignas(16) f16 X16[2][64][132];    // x16[b][j]
  __shared__ alignas(16) f16 Xt16[2][128][68];   // x16[b][j] stored [j][b]
  __shared__ alignas(16) float theta[128];
  __shared__ alignas(16) float pairs[4][64][2];  // per-wave (q, ypred) partials
  __shared__ alignas(16) float rden_err[64][2];  // (rd, err) per b

  const int tid = threadIdx.x;
  const int w = tid >> 6;        // wave id = owned i-tile
  const int lane = tid & 63;
  const int l31 = lane & 31;
  const int h = lane >> 5;
  const int i32 = 32 * w + l31;  // this lane's P row index i

  // Pacc tile jm, element r  <->  Pt[i32][j], j = 32*jm + (r&3) + 8*(r>>2) + 4*h
  f32x16 Pacc[4];
#pragma unroll
  for (int jm = 0; jm < 4; ++jm)
#pragma unroll
    for (int r = 0; r < 16; ++r) {
      const int j = 32 * jm + (r & 3) + 8 * (r >> 2) + 4 * h;
      Pacc[jm][r] = (j == i32) ? 100.0f : 0.0f;  // P0 = I/lambda, ft0 = 1
    }
  if (tid < 128) theta[tid] = 0.0f;

  // x prefetch mapping: thread covers rows (2p, 2p+1), cols 16*jbk..16*jbk+15
  const int p = l31;
  const int jbk = 2 * w + h;
  const long rstride = (long)T_N * D_N;
  const float* xrow0 = xg + (long)(2 * p) * rstride + 16 * jbk;

  float4 xr[8];
  float tcur = 0.0f, tnxt = 0.0f;
  float ft = 1.0f;  // FF^t
  int pb = 0;

#define XLOAD(tt)                                                     \
  {                                                                   \
    _Pragma("unroll") for (int q = 0; q < 4; ++q) {                   \
      xr[q] = *(const float4*)(xrow0 + (long)(tt)*D_N + 4 * q);       \
      xr[4 + q] = *(const float4*)(xrow0 + rstride + (long)(tt)*D_N + 4 * q); \
    }                                                                 \
  }

#define XPREP(bidx)                                                   \
  {                                                                   \
    f16 c0[16], c1[16];                                               \
    _Pragma("unroll") for (int q = 0; q < 4; ++q) {                   \
      const float* f0 = (const float*)&xr[q];                         \
      const float* f1 = (const float*)&xr[4 + q];                     \
      _Pragma("unroll") for (int e = 0; e < 4; ++e) {                 \
        c0[4 * q + e] = (f16)f0[e];                                   \
        c1[4 * q + e] = (f16)f1[e];                                   \
      }                                                               \
    }                                                                 \
    _Pragma("unroll") for (int q = 0; q < 4; ++q) {                   \
      f16x4 v0 = {c0[4 * q], c0[4 * q + 1], c0[4 * q + 2], c0[4 * q + 3]}; \
      f16x4 v1 = {c1[4 * q], c1[4 * q + 1], c1[4 * q + 2], c1[4 * q + 3]}; \
      *(f16x4*)&X16[bidx][2 * p][16 * jbk + 4 * q] = v0;              \
      *(f16x4*)&X16[bidx][2 * p + 1][16 * jbk + 4 * q] = v1;          \
    }                                                                 \
    _Pragma("unroll") for (int c = 0; c < 16; ++c) {                  \
      *(u32*)&Xt16[bidx][16 * jbk + c][2 * p] = pk2(c0[c], c1[c]);    \
    }                                                                 \
  }

  // prologue: stage x(0), tgt(0) into buffer 0
  XLOAD(0);
  if (tid < B_N) tcur = tg[(long)tid * T_N];
  XPREP(0);
  __syncthreads();

  for (int t = 0; t < T_N; ++t) {
    // ---- (A) issue prefetch of x(t+1), tgt(t+1)
    if (t + 1 < T_N) {
      XLOAD(t + 1);
      if (tid < B_N) tnxt = tg[(long)tid * T_N + (t + 1)];
    }

    // ---- (B) pack Pt into f16 hi/lo pair quads (pkrtz; residual exact)
    u32 pqh[4][4][2], pql[4][4][2];
#pragma unroll
    for (int jm = 0; jm < 4; ++jm)
#pragma unroll
      for (int rq = 0; rq < 4; ++rq) {
        const float v0 = Pacc[jm][4 * rq + 0], v1 = Pacc[jm][4 * rq + 1];
        const float v2 = Pacc[jm][4 * rq + 2], v3 = Pacc[jm][4 * rq + 3];
        const u32 h0 = pkrtz(v0, v1), h1 = pkrtz(v2, v3);
        const f16* hp0 = (const f16*)&h0;
        const f16* hp1 = (const f16*)&h1;
        pqh[jm][rq][0] = h0;
        pqh[jm][rq][1] = h1;
        pql[jm][rq][0] = pkrtz(v0 - (float)hp0[0], v1 - (float)hp0[1]);
        pql[jm][rq][1] = pkrtz(v2 - (float)hp1[0], v3 - (float)hp1[1]);
      }

    // ---- (C) m1: acc1 = X*Pt^T (hi+lo)  and  m1': accT = Pt*X^T (hi only)
    // Same bfrag fragments serve as B-op (m1) and A-op (m1'); same X16 reads
    // serve as A-op (m1) and B-op (m1').
    f32x16 acc1[2], accT[2];
#pragma unroll
    for (int r = 0; r < 16; ++r) {
      acc1[0][r] = 0.0f; acc1[1][r] = 0.0f;
      accT[0][r] = 0.0f; accT[1][r] = 0.0f;
    }
#pragma unroll
    for (int ks = 0; ks < 8; ++ks) {
      const int a = ks >> 1, s = 2 * (ks & 1);
      f16x8 bh = bfrag(h, pqh[a][s][0], pqh[a][s][1], pqh[a][s + 1][0], pqh[a][s + 1][1]);
      f16x8 bl = bfrag(h, pql[a][s][0], pql[a][s][1], pql[a][s + 1][0], pql[a][s + 1][1]);
      const int j0 = 16 * ks + 8 * h;
      f16x8 a0 = cat8(*(const f16x4*)&X16[pb][l31][j0], *(const f16x4*)&X16[pb][l31][j0 + 4]);
      f16x8 a1 = cat8(*(const f16x4*)&X16[pb][32 + l31][j0], *(const f16x4*)&X16[pb][32 + l31][j0 + 4]);
      acc1[0] = __builtin_amdgcn_mfma_f32_32x32x16_f16(a0, bh, acc1[0], 0, 0, 0);
      acc1[0] = __builtin_amdgcn_mfma_f32_32x32x16_f16(a0, bl, acc1[0], 0, 0, 0);
      acc1[1] = __builtin_amdgcn_mfma_f32_32x32x16_f16(a1, bh, acc1[1], 0, 0, 0);
      acc1[1] = __builtin_amdgcn_mfma_f32_32x32x16_f16(a1, bl, acc1[1], 0, 0, 0);
      accT[0] = __builtin_amdgcn_mfma_f32_32x32x16_f16(bh, a0, accT[0], 0, 0, 0);
      accT[1] = __builtin_amdgcn_mfma_f32_32x32x16_f16(bh, a1, accT[1], 0, 0, 0);
    }

    // ---- (D) q = x'Ptx and y = x'theta per b: in-lane over regs (i), one
    // half-swap, then one LDS write per (wave, b). accT[bt] reg r, lane(l31,h):
    // i = 32w + (r&3)+8*(r>>2)+4h, b = 32bt + l31.
#pragma unroll
    for (int bt = 0; bt < 2; ++bt) {
      const f16* xrow = &X16[pb][32 * bt + l31][0];
      float q = 0.0f, y = 0.0f;
#pragma unroll
      for (int rq = 0; rq < 4; ++rq) {
        const int jj = 32 * w + 8 * rq + 4 * h;
        const f16x4 xq = *(const f16x4*)&xrow[jj];
        const float4 tq = *(const float4*)&theta[jj];
        const float* tqf = (const float*)&tq;
#pragma unroll
        for (int c = 0; c < 4; ++c) {
          const float xf = (float)xq[c];
          q = fmaf(xf, accT[bt][4 * rq + c], q);
          y = fmaf(xf, tqf[c], y);
        }
      }
      q += sx32f(q);  // partner half covers the other (i mod 8) half
      y += sx32f(y);
      if (h == 0) {
        float2 v; v.x = q; v.y = y;
        *(float2*)&pairs[w][32 * bt + l31][0] = v;
      }
    }
    wg_barrier();

    // ---- (E) finalize per-b scalars, emit raw attention
    if (tid < B_N) {
      float qs = 0.0f, ys = 0.0f;
#pragma unroll
      for (int ww = 0; ww < 4; ++ww) {
        const float2 v = *(const float2*)&pairs[ww][tid][0];
        qs += v.x; ys += v.y;
      }
      const float rd = 1.0f / (qs + FEPS * ft);
      rden_err[tid][0] = rd;
      rden_err[tid][1] = tcur - ys;
      attn[(long)tid * T_N + t] = ys;
    }
    wg_barrier();

    // ---- (F) K = Ptx*rd, theta update, pack km = -ft*K/B (hi only)
    const float negsc = -ft * INVB;
    u32 kq[2][4][2];
    float tsum = 0.0f;
#pragma unroll
    for (int bm = 0; bm < 2; ++bm)
#pragma unroll
      for (int rq = 0; rq < 4; ++rq) {
        const int b0 = 32 * bm + 8 * rq + 4 * h;
        const float4 q0 = *(const float4*)&rden_err[b0][0];      // rd0,e0,rd1,e1
        const float4 q1 = *(const float4*)&rden_err[b0 + 2][0];  // rd2,e2,rd3,e3
        float kr[4];
        kr[0] = acc1[bm][4 * rq + 0] * q0.x;
        kr[1] = acc1[bm][4 * rq + 1] * q0.z;
        kr[2] = acc1[bm][4 * rq + 2] * q1.x;
        kr[3] = acc1[bm][4 * rq + 3] * q1.z;
        tsum += kr[0] * q0.y + kr[1] * q0.w + kr[2] * q1.y + kr[3] * q1.w;
        kq[bm][rq][0] = pkrtz(kr[0] * negsc, kr[1] * negsc);
        kq[bm][rq][1] = pkrtz(kr[2] * negsc, kr[3] * negsc);
      }
    tsum += sx32f(tsum);
    if (h == 0) theta[i32] += tsum * INVB;  // wave-private range: no barrier needed

    // ---- (X) stage x(t+1) into the other buffer (overlaps with G)
    if (t + 1 < T_N) {
      XPREP(pb ^ 1);
      tcur = tnxt;
    }

    // ---- (G) m2: Pt += Xt * km  (hi only)
#pragma unroll
    for (int ks = 0; ks < 4; ++ks) {
      const int a = ks >> 1, s = 2 * (ks & 1);
      f16x8 bh = bfrag(h, kq[a][s][0], kq[a][s][1], kq[a][s + 1][0], kq[a][s + 1][1]);
      const int b0 = 16 * ks + 8 * h;
#pragma unroll
      for (int jm = 0; jm < 4; ++jm) {
        f16x8 a2 = cat8(*(const f16x4*)&Xt16[pb][32 * jm + l31][b0],
                        *(const f16x4*)&Xt16[pb][32 * jm + l31][b0 + 4]);
        Pacc[jm] = __builtin_amdgcn_mfma_f32_32x32x16_f16(a2, bh, Pacc[jm], 0, 0, 0);
      }
    }
    wg_barrier();

    pb ^= 1;
    ft *= FF;
  }
#undef XLOAD
#undef XPREP
}

// softmax over time per batch row (in place on raw attn)
__global__ void softmax_k(float* __restrict__ attn) {
  const int b = blockIdx.x;
  float* row = attn + (long)b * T_N;
  __shared__ float sv[T_N];
  __shared__ float red[256];
  const int tid = threadIdx.x;
  float m = -1e30f;
  for (int k = tid; k < T_N; k += 256) {
    const float v = row[k];
    sv[k] = v;
    m = fmaxf(m, v);
  }
  red[tid] = m;
  __syncthreads();
  for (int off = 128; off > 0; off >>= 1) {
    if (tid < off) red[tid] = fmaxf(red[tid], red[tid + off]);
    __syncthreads();
  }
  const float M = red[0];
  __syncthreads();
  float s = 0.0f;
  for (int k = tid; k < T_N; k += 256) {
    const float e = __expf(sv[k] - M);
    sv[k] = e;
    s += e;
  }
  red[tid] = s;
  __syncthreads();
  for (int off = 128; off > 0; off >>= 1) {
    if (tid < off) red[tid] += red[tid + off];
    __syncthreads();
  }
  const float inv = 1.0f / red[0];
  for (int k = tid; k < T_N; k += 256) row[k] = sv[k] * inv;
}

// out[b][d] = sum_t x[b][t][d] * attn_norm[b][t]
__global__ void einsum_k(const float* __restrict__ xg,
                         const float* __restrict__ attn,
                         float* __restrict__ out) {
  const int b = blockIdx.x;
  const int d = threadIdx.x;  // 128 threads
  __shared__ float as[T_N];
  for (int k = d; k < T_N; k += 128) as[k] = attn[(long)b * T_N + k];
  __syncthreads();
  const float* xb = xg + (long)b * T_N * D_N + d;
  float acc = 0.0f;
#pragma unroll 4
  for (int t = 0; t < T_N; ++t) acc += xb[(long)t * D_N] * as[t];
  out[b * D_N + d] = acc;
}

extern "C" void kernel_launch(void* const* d_in, const int* in_sizes, int n_in,
                              void* d_out, int out_size, void* d_ws, size_t ws_size,
                              hipStream_t stream) {
  const float* x = (const float*)d_in[0];
  const float* tgt = (const float*)d_in[1];
  float* out = (float*)d_out;
  float* attn = out + B_N * D_N;  // outputs: [output (B,D) | attn_norm (B,T)]

  rls_seq<<<dim3(1), dim3(256), 0, stream>>>(x, tgt, attn);
  softmax_k<<<dim3(B_N), dim3(256), 0, stream>>>(attn);
  einsum_k<<<dim3(B_N), dim3(128), 0, stream>>>(x, attn, out);
}

// Round 6
// 12724.472 us; speedup vs baseline: 2.7858x; 1.4518x over previous
//
#include <hip/hip_runtime.h>

#define T_N 4096
#define B_N 64
#define D_N 128

typedef _Float16 f16;
typedef _Float16 f16x4 __attribute__((ext_vector_type(4)));
typedef _Float16 f16x8 __attribute__((ext_vector_type(8)));
typedef __fp16 fp16x2 __attribute__((ext_vector_type(2)));
typedef float f32x16 __attribute__((ext_vector_type(16)));
typedef unsigned int u32;
typedef unsigned int u32x2 __attribute__((ext_vector_type(2)));

__device__ __forceinline__ f16x8 cat8(f16x4 a, f16x4 b) {
  return __builtin_shufflevector(a, b, 0, 1, 2, 3, 4, 5, 6, 7);
}
__device__ __forceinline__ u32 pk2(f16 a, f16 b) {
  union { f16 x[2]; u32 u; } z;
  z.x[0] = a; z.x[1] = b;
  return z.u;
}
__device__ __forceinline__ u32 pkrtz(float a, float b) {
  union { fp16x2 h; u32 u; } z;
  z.h = __builtin_amdgcn_cvt_pkrtz(a, b);
  return z.u;
}
__device__ __forceinline__ float sx32f(float v) {
  return __shfl_xor(v, 32, 64);
}

// raw barrier: LDS-visibility only; does NOT drain vmcnt (prefetch stays in flight)
__device__ __forceinline__ void wg_barrier() {
  asm volatile("s_waitcnt lgkmcnt(0)" ::: "memory");
  __builtin_amdgcn_sched_barrier(0);
  __builtin_amdgcn_s_barrier();
  __builtin_amdgcn_sched_barrier(0);
}

// B/A fragment builder: element e at lane (l31,h) = quad-data for k-offset 8h+e
// within a 16-wide k-window. qs = quad rq=s, qt = quad rq=s+1.
__device__ __forceinline__ f16x8 bfrag(int h, u32 qs0, u32 qs1, u32 qt0, u32 qt1) {
  u32x2 s0 = __builtin_amdgcn_permlane32_swap(qs0, qt0, false, false);
  u32x2 s1 = __builtin_amdgcn_permlane32_swap(qs1, qt1, false, false);
  union { u32 u[4]; f16x8 v; } z;
  z.u[0] = s0[0]; z.u[1] = s1[0]; z.u[2] = s0[1]; z.u[3] = s1[1];
  return z.v;
}

// Sequential RLS scan: 8 waves. Waves 0-3 ("P-waves") hold Pt = FF^t * P in
// MFMA accumulators and run the serial recurrence; waves 4-7 ("IO-waves")
// stage x(t+1) (global->f16 LDS incl. transpose), load targets, compute the
// per-b denominators/errors (phase E), and store attn. All matmuls hi-f16 only
// (x itself is f16-quantized at 5e-4 rel; lo-terms measured noise-level).
__global__ __launch_bounds__(512, 2) void rls_seq(
    const float* __restrict__ xg, const float* __restrict__ tg,
    float* __restrict__ attn) {
  constexpr float FF = 0.99f, EPS = 1e-8f;
  constexpr float FEPS = FF + EPS;
  constexpr float INVB = 1.0f / 64.0f;

  // double-buffered X tiles; u32-strides mod 4 == 2 -> 2-way (free) bank aliasing
  __shared__ alignas(16) f16 X16[2][64][132];    // x16[b][j]
  __shared__ alignas(16) f16 Xt16[2][128][68];   // x16[b][j] stored [j][b]
  __shared__ alignas(16) float theta[128];
  __shared__ alignas(16) float pairs[4][64][2];  // per-P-wave (q, ypred) partials
  __shared__ alignas(16) float rden_err[64][2];  // (rd, err) per b

  const int tid = threadIdx.x;
  const int wid = tid >> 6;       // 0..3 P-waves, 4..7 IO-waves
  const int lane = tid & 63;
  const int l31 = lane & 31;
  const int h = lane >> 5;
  const int w = wid & 3;          // P: owned i-tile. IO: staging column group.
  const int i32 = 32 * w + l31;   // P-wave: this lane's P row index i

  // Pacc tile jm, element r  <->  Pt[i32][j], j = 32*jm + (r&3) + 8*(r>>2) + 4*h
  f32x16 Pacc[4];
  if (wid < 4) {
#pragma unroll
    for (int jm = 0; jm < 4; ++jm)
#pragma unroll
      for (int r = 0; r < 16; ++r) {
        const int j = 32 * jm + (r & 3) + 8 * (r >> 2) + 4 * h;
        Pacc[jm][r] = (j == i32) ? 100.0f : 0.0f;  // P0 = I/lambda, ft0 = 1
      }
    if (tid < 128) theta[tid] = 0.0f;
  }

  // staging mapping (IO-waves): thread covers rows (2p,2p+1), cols 16*jbk..+15
  const int p = l31;
  const int jbk = 2 * w + h;
  const long rstride = (long)T_N * D_N;
  const float* xrow0 = xg + (long)(2 * p) * rstride + 16 * jbk;

  float4 xr[8];
  float tcur = 0.0f, tnxt = 0.0f;
  float ft = 1.0f;  // FF^t
  int pb = 0;

#define XLOAD(tt)                                                     \
  {                                                                   \
    _Pragma("unroll") for (int q = 0; q < 4; ++q) {                   \
      xr[q] = *(const float4*)(xrow0 + (long)(tt)*D_N + 4 * q);       \
      xr[4 + q] = *(const float4*)(xrow0 + rstride + (long)(tt)*D_N + 4 * q); \
    }                                                                 \
  }

#define XPREP(bidx)                                                   \
  {                                                                   \
    f16 c0[16], c1[16];                                               \
    _Pragma("unroll") for (int q = 0; q < 4; ++q) {                   \
      const float* f0 = (const float*)&xr[q];                         \
      const float* f1 = (const float*)&xr[4 + q];                     \
      _Pragma("unroll") for (int e = 0; e < 4; ++e) {                 \
        c0[4 * q + e] = (f16)f0[e];                                   \
        c1[4 * q + e] = (f16)f1[e];                                   \
      }                                                               \
    }                                                                 \
    _Pragma("unroll") for (int q = 0; q < 4; ++q) {                   \
      f16x4 v0 = {c0[4 * q], c0[4 * q + 1], c0[4 * q + 2], c0[4 * q + 3]}; \
      f16x4 v1 = {c1[4 * q], c1[4 * q + 1], c1[4 * q + 2], c1[4 * q + 3]}; \
      *(f16x4*)&X16[bidx][2 * p][16 * jbk + 4 * q] = v0;              \
      *(f16x4*)&X16[bidx][2 * p + 1][16 * jbk + 4 * q] = v1;          \
    }                                                                 \
    _Pragma("unroll") for (int c = 0; c < 16; ++c) {                  \
      *(u32*)&Xt16[bidx][16 * jbk + c][2 * p] = pk2(c0[c], c1[c]);    \
    }                                                                 \
  }

  // prologue: IO-waves stage x(0), tgt(0) into buffer 0; P-waves get priority
  if (wid >= 4) {
    XLOAD(0);
    if (wid == 4) tcur = tg[(long)lane * T_N];
    XPREP(0);
  } else {
    __builtin_amdgcn_s_setprio(1);
  }
  __syncthreads();

  for (int t = 0; t < T_N; ++t) {
    f32x16 acc1[2];  // Px: live across barriers into phase F

    // ================= phase 1 =================
    if (wid < 4) {
      // ---- a-fragment prefetch for C (latency covered by the pack below)
      f16x4 ar[8][4];
#pragma unroll
      for (int ks = 0; ks < 8; ++ks) {
        const int j0 = 16 * ks + 8 * h;
        ar[ks][0] = *(const f16x4*)&X16[pb][l31][j0];
        ar[ks][1] = *(const f16x4*)&X16[pb][l31][j0 + 4];
        ar[ks][2] = *(const f16x4*)&X16[pb][32 + l31][j0];
        ar[ks][3] = *(const f16x4*)&X16[pb][32 + l31][j0 + 4];
      }

      // ---- (B) pack Pt into f16 pair quads (hi only)
      u32 pqh[4][4][2];
#pragma unroll
      for (int jm = 0; jm < 4; ++jm)
#pragma unroll
        for (int rq = 0; rq < 4; ++rq) {
          pqh[jm][rq][0] = pkrtz(Pacc[jm][4 * rq + 0], Pacc[jm][4 * rq + 1]);
          pqh[jm][rq][1] = pkrtz(Pacc[jm][4 * rq + 2], Pacc[jm][4 * rq + 3]);
        }

      // ---- (C) m1: acc1 = X*Pt^T  and  m1': accT = Pt*X^T (for q,y reduction)
      f32x16 accT[2];
#pragma unroll
      for (int r = 0; r < 16; ++r) {
        acc1[0][r] = 0.0f; acc1[1][r] = 0.0f;
        accT[0][r] = 0.0f; accT[1][r] = 0.0f;
      }
#pragma unroll
      for (int ks = 0; ks < 8; ++ks) {
        const int a = ks >> 1, s = 2 * (ks & 1);
        f16x8 bh = bfrag(h, pqh[a][s][0], pqh[a][s][1], pqh[a][s + 1][0], pqh[a][s + 1][1]);
        f16x8 a0 = cat8(ar[ks][0], ar[ks][1]);
        f16x8 a1 = cat8(ar[ks][2], ar[ks][3]);
        acc1[0] = __builtin_amdgcn_mfma_f32_32x32x16_f16(a0, bh, acc1[0], 0, 0, 0);
        acc1[1] = __builtin_amdgcn_mfma_f32_32x32x16_f16(a1, bh, acc1[1], 0, 0, 0);
        accT[0] = __builtin_amdgcn_mfma_f32_32x32x16_f16(bh, a0, accT[0], 0, 0, 0);
        accT[1] = __builtin_amdgcn_mfma_f32_32x32x16_f16(bh, a1, accT[1], 0, 0, 0);
      }

      // ---- (D) q = x'Ptx, y = x'theta per b: in-lane over regs (i), one
      // half-swap, one LDS write per (wave,b). accT[bt] reg r, lane(l31,h):
      // i = 32w + (r&3)+8*(r>>2)+4h, b = 32bt + l31.
      f16x4 xq[2][4];
      float4 tq[4];
#pragma unroll
      for (int rq = 0; rq < 4; ++rq) {
        const int jj = 32 * w + 8 * rq + 4 * h;
        tq[rq] = *(const float4*)&theta[jj];
        xq[0][rq] = *(const f16x4*)&X16[pb][l31][jj];
        xq[1][rq] = *(const f16x4*)&X16[pb][32 + l31][jj];
      }
#pragma unroll
      for (int bt = 0; bt < 2; ++bt) {
        float q = 0.0f, y = 0.0f;
#pragma unroll
        for (int rq = 0; rq < 4; ++rq) {
          const float* tqf = (const float*)&tq[rq];
#pragma unroll
          for (int c = 0; c < 4; ++c) {
            const float xf = (float)xq[bt][rq][c];
            q = fmaf(xf, accT[bt][4 * rq + c], q);
            y = fmaf(xf, tqf[c], y);
          }
        }
        q += sx32f(q);
        y += sx32f(y);
        if (h == 0) {
          float2 v; v.x = q; v.y = y;
          *(float2*)&pairs[w][32 * bt + l31][0] = v;
        }
      }
    } else {
      // IO: issue prefetch of x(t+1), tgt(t+1) (vmcnt stays in flight)
      if (t + 1 < T_N) {
        XLOAD(t + 1);
        if (wid == 4) tnxt = tg[(long)lane * T_N + (t + 1)];
      }
    }
    wg_barrier();

    // ================= phase E (IO wave 4) =================
    if (wid == 4) {
      const int b = lane;
      float qs = 0.0f, ys = 0.0f;
#pragma unroll
      for (int ww = 0; ww < 4; ++ww) {
        const float2 v = *(const float2*)&pairs[ww][b][0];
        qs += v.x; ys += v.y;
      }
      const float rd = 1.0f / (qs + FEPS * ft);
      rden_err[b][0] = rd;
      rden_err[b][1] = tcur - ys;
      attn[(long)b * T_N + t] = ys;
    }
    wg_barrier();

    // ================= phase 2 =================
    if (wid < 4) {
      // ---- Xt-fragment prefetch for G (latency covered by F below)
      f16x4 xt[4][4][2];
#pragma unroll
      for (int ks = 0; ks < 4; ++ks) {
        const int b0 = 16 * ks + 8 * h;
#pragma unroll
        for (int jm = 0; jm < 4; ++jm) {
          xt[ks][jm][0] = *(const f16x4*)&Xt16[pb][32 * jm + l31][b0];
          xt[ks][jm][1] = *(const f16x4*)&Xt16[pb][32 * jm + l31][b0 + 4];
        }
      }

      // ---- (F) K = Ptx*rd, theta update, pack km = -ft*K/B (hi only)
      const float negsc = -ft * INVB;
      u32 kq[2][4][2];
      float tsum = 0.0f;
#pragma unroll
      for (int bm = 0; bm < 2; ++bm)
#pragma unroll
        for (int rq = 0; rq < 4; ++rq) {
          const int b0 = 32 * bm + 8 * rq + 4 * h;
          const float4 q0 = *(const float4*)&rden_err[b0][0];      // rd0,e0,rd1,e1
          const float4 q1 = *(const float4*)&rden_err[b0 + 2][0];  // rd2,e2,rd3,e3
          float kr[4];
          kr[0] = acc1[bm][4 * rq + 0] * q0.x;
          kr[1] = acc1[bm][4 * rq + 1] * q0.z;
          kr[2] = acc1[bm][4 * rq + 2] * q1.x;
          kr[3] = acc1[bm][4 * rq + 3] * q1.z;
          tsum += kr[0] * q0.y + kr[1] * q0.w + kr[2] * q1.y + kr[3] * q1.w;
          kq[bm][rq][0] = pkrtz(kr[0] * negsc, kr[1] * negsc);
          kq[bm][rq][1] = pkrtz(kr[2] * negsc, kr[3] * negsc);
        }
      tsum += sx32f(tsum);
      if (h == 0) theta[i32] += tsum * INVB;  // wave-private range

      // ---- (G) m2: Pt += Xt * km  (hi only)
#pragma unroll
      for (int ks = 0; ks < 4; ++ks) {
        const int a = ks >> 1, s = 2 * (ks & 1);
        f16x8 bh = bfrag(h, kq[a][s][0], kq[a][s][1], kq[a][s + 1][0], kq[a][s + 1][1]);
#pragma unroll
        for (int jm = 0; jm < 4; ++jm) {
          f16x8 a2 = cat8(xt[ks][jm][0], xt[ks][jm][1]);
          Pacc[jm] = __builtin_amdgcn_mfma_f32_32x32x16_f16(a2, bh, Pacc[jm], 0, 0, 0);
        }
      }
    } else {
      // IO: stage x(t+1) into the other buffer (waits vmcnt internally)
      if (t + 1 < T_N) {
        XPREP(pb ^ 1);
      }
      tcur = tnxt;
    }
    wg_barrier();

    pb ^= 1;
    ft *= FF;
  }
#undef XLOAD
#undef XPREP
}

// softmax over time per batch row (in place on raw attn)
__global__ void softmax_k(float* __restrict__ attn) {
  const int b = blockIdx.x;
  float* row = attn + (long)b * T_N;
  __shared__ float sv[T_N];
  __shared__ float red[256];
  const int tid = threadIdx.x;
  float m = -1e30f;
  for (int k = tid; k < T_N; k += 256) {
    const float v = row[k];
    sv[k] = v;
    m = fmaxf(m, v);
  }
  red[tid] = m;
  __syncthreads();
  for (int off = 128; off > 0; off >>= 1) {
    if (tid < off) red[tid] = fmaxf(red[tid], red[tid + off]);
    __syncthreads();
  }
  const float M = red[0];
  __syncthreads();
  float s = 0.0f;
  for (int k = tid; k < T_N; k += 256) {
    const float e = __expf(sv[k] - M);
    sv[k] = e;
    s += e;
  }
  red[tid] = s;
  __syncthreads();
  for (int off = 128; off > 0; off >>= 1) {
    if (tid < off) red[tid] += red[tid + off];
    __syncthreads();
  }
  const float inv = 1.0f / red[0];
  for (int k = tid; k < T_N; k += 256) row[k] = sv[k] * inv;
}

// out[b][d] = sum_t x[b][t][d] * attn_norm[b][t]
__global__ void einsum_k(const float* __restrict__ xg,
                         const float* __restrict__ attn,
                         float* __restrict__ out) {
  const int b = blockIdx.x;
  const int d = threadIdx.x;  // 128 threads
  __shared__ float as[T_N];
  for (int k = d; k < T_N; k += 128) as[k] = attn[(long)b * T_N + k];
  __syncthreads();
  const float* xb = xg + (long)b * T_N * D_N + d;
  float acc = 0.0f;
#pragma unroll 4
  for (int t = 0; t < T_N; ++t) acc += xb[(long)t * D_N] * as[t];
  out[b * D_N + d] = acc;
}

extern "C" void kernel_launch(void* const* d_in, const int* in_sizes, int n_in,
                              void* d_out, int out_size, void* d_ws, size_t ws_size,
                              hipStream_t stream) {
  const float* x = (const float*)d_in[0];
  const float* tgt = (const float*)d_in[1];
  float* out = (float*)d_out;
  float* attn = out + B_N * D_N;  // outputs: [output (B,D) | attn_norm (B,T)]

  rls_seq<<<dim3(1), dim3(512), 0, stream>>>(x, tgt, attn);
  softmax_k<<<dim3(B_N), dim3(256), 0, stream>>>(attn);
  einsum_k<<<dim3(B_N), dim3(128), 0, stream>>>(x, attn, out);
}

// Round 7
// 11972.134 us; speedup vs baseline: 2.9608x; 1.0628x over previous
//
#include <hip/hip_runtime.h>

#define T_N 4096
#define B_N 64
#define D_N 128

typedef _Float16 f16;
typedef _Float16 f16x4 __attribute__((ext_vector_type(4)));
typedef _Float16 f16x8 __attribute__((ext_vector_type(8)));
typedef __fp16 fp16x2 __attribute__((ext_vector_type(2)));
typedef float f32x16 __attribute__((ext_vector_type(16)));
typedef unsigned int u32;
typedef unsigned int u32x2 __attribute__((ext_vector_type(2)));

__device__ __forceinline__ f16x8 cat8(f16x4 a, f16x4 b) {
  return __builtin_shufflevector(a, b, 0, 1, 2, 3, 4, 5, 6, 7);
}
__device__ __forceinline__ u32 pk2(f16 a, f16 b) {
  union { f16 x[2]; u32 u; } z;
  z.x[0] = a; z.x[1] = b;
  return z.u;
}
__device__ __forceinline__ u32 pkrtz(float a, float b) {
  union { fp16x2 h; u32 u; } z;
  z.h = __builtin_amdgcn_cvt_pkrtz(a, b);
  return z.u;
}
__device__ __forceinline__ float sx32f(float v) {
  return __shfl_xor(v, 32, 64);
}

// raw barrier: LDS-visibility only; does NOT drain vmcnt (prefetch stays in flight)
__device__ __forceinline__ void wg_barrier() {
  asm volatile("s_waitcnt lgkmcnt(0)" ::: "memory");
  __builtin_amdgcn_sched_barrier(0);
  __builtin_amdgcn_s_barrier();
  __builtin_amdgcn_sched_barrier(0);
}

// B/A fragment builder: element e at lane (l31,h) = quad-data for k-offset 8h+e
// within a 16-wide k-window. qs = quad rq=s, qt = quad rq=s+1.
__device__ __forceinline__ f16x8 bfrag(int h, u32 qs0, u32 qs1, u32 qt0, u32 qt1) {
  u32x2 s0 = __builtin_amdgcn_permlane32_swap(qs0, qt0, false, false);
  u32x2 s1 = __builtin_amdgcn_permlane32_swap(qs1, qt1, false, false);
  union { u32 u[4]; f16x8 v; } z;
  z.u[0] = s0[0]; z.u[1] = s1[0]; z.u[2] = s0[1]; z.u[3] = s1[1];
  return z.v;
}

// Sequential RLS scan: 8 waves. Waves 0-3 ("P-waves") hold Pt = FF^t * P in
// MFMA accumulators and run the serial recurrence; waves 4-7 ("IO-waves")
// stage x(t+1) (global->f16 LDS incl. transpose) and store attn (wave 4).
// Two raw barriers per step; the per-b scalar reduction (denom/err) is done
// redundantly per P-wave into a private LDS strip (no barrier, no serial wave).
__global__ __launch_bounds__(512, 1) void rls_seq(
    const float* __restrict__ xg, const float* __restrict__ tg,
    float* __restrict__ attn) {
  constexpr float FF = 0.99f, EPS = 1e-8f;
  constexpr float FEPS = FF + EPS;
  constexpr float INVB = 1.0f / 64.0f;

  // double-buffered X tiles; u32-strides mod 4 == 2 -> 2-way (free) bank aliasing
  __shared__ alignas(16) f16 X16[2][64][132];    // x16[b][j]
  __shared__ alignas(16) f16 Xt16[2][128][68];   // x16[b][j] stored [j][b]
  __shared__ alignas(16) float theta[128];
  __shared__ alignas(16) float pairs[4][64][2];  // per-P-wave (q, ypred) partials
  __shared__ alignas(16) float rw[4][64][2];     // per-P-wave private (rd, err)

  const int tid = threadIdx.x;
  const int wid = tid >> 6;       // 0..3 P-waves, 4..7 IO-waves
  const int lane = tid & 63;
  const int l31 = lane & 31;
  const int h = lane >> 5;
  const int w = wid & 3;          // P: owned i-tile. IO: staging column group.
  const int i32 = 32 * w + l31;   // P-wave: this lane's P row index i

  // Pacc tile jm, element r  <->  Pt[i32][j], j = 32*jm + (r&3) + 8*(r>>2) + 4*h
  f32x16 Pacc[4];
  if (wid < 4) {
#pragma unroll
    for (int jm = 0; jm < 4; ++jm)
#pragma unroll
      for (int r = 0; r < 16; ++r) {
        const int j = 32 * jm + (r & 3) + 8 * (r >> 2) + 4 * h;
        Pacc[jm][r] = (j == i32) ? 100.0f : 0.0f;  // P0 = I/lambda, ft0 = 1
      }
    if (tid < 128) theta[tid] = 0.0f;
  }

  // staging mapping (IO-waves): thread covers rows (2p,2p+1), cols 16*jbk..+15
  const int p = l31;
  const int jbk = 2 * w + h;
  const long rstride = (long)T_N * D_N;
  const float* xrow0 = xg + (long)(2 * p) * rstride + 16 * jbk;

  float4 xr[8];
  float tcur = 0.0f, tnxt = 0.0f;
  float ft = 1.0f;  // FF^t
  int pb = 0;

  f32x16 Z;  // persistent zero accumulator (saves per-step v_mov zero-init)
#pragma unroll
  for (int r = 0; r < 16; ++r) Z[r] = 0.0f;

#define XLOAD(tt)                                                     \
  {                                                                   \
    _Pragma("unroll") for (int q = 0; q < 4; ++q) {                   \
      xr[q] = *(const float4*)(xrow0 + (long)(tt)*D_N + 4 * q);       \
      xr[4 + q] = *(const float4*)(xrow0 + rstride + (long)(tt)*D_N + 4 * q); \
    }                                                                 \
  }

#define XPREP(bidx)                                                   \
  {                                                                   \
    f16 c0[16], c1[16];                                               \
    _Pragma("unroll") for (int q = 0; q < 4; ++q) {                   \
      const float* f0 = (const float*)&xr[q];                         \
      const float* f1 = (const float*)&xr[4 + q];                     \
      _Pragma("unroll") for (int e = 0; e < 4; ++e) {                 \
        c0[4 * q + e] = (f16)f0[e];                                   \
        c1[4 * q + e] = (f16)f1[e];                                   \
      }                                                               \
    }                                                                 \
    _Pragma("unroll") for (int q = 0; q < 4; ++q) {                   \
      f16x4 v0 = {c0[4 * q], c0[4 * q + 1], c0[4 * q + 2], c0[4 * q + 3]}; \
      f16x4 v1 = {c1[4 * q], c1[4 * q + 1], c1[4 * q + 2], c1[4 * q + 3]}; \
      *(f16x4*)&X16[bidx][2 * p][16 * jbk + 4 * q] = v0;              \
      *(f16x4*)&X16[bidx][2 * p + 1][16 * jbk + 4 * q] = v1;          \
    }                                                                 \
    _Pragma("unroll") for (int c = 0; c < 16; ++c) {                  \
      *(u32*)&Xt16[bidx][16 * jbk + c][2 * p] = pk2(c0[c], c1[c]);    \
    }                                                                 \
  }

  // prologue: IO-waves stage x(0) into buffer 0; P-waves load tgt(0), get prio
  if (wid >= 4) {
    XLOAD(0);
    XPREP(0);
  } else {
    __builtin_amdgcn_s_setprio(1);
    tcur = tg[(long)lane * T_N];
  }
  __syncthreads();

  for (int t = 0; t < T_N; ++t) {
    f32x16 acc1[2];  // Px: live across the barrier into phase F

    // ================= phase 1 =================
    if (wid < 4) {
      // tgt prefetch for t+1 (used next step; latency fully covered)
      if (t + 1 < T_N) tnxt = tg[(long)lane * T_N + (t + 1)];

      // ---- a-fragment prefetch for C (latency covered by the pack below)
      f16x4 ar[8][4];
#pragma unroll
      for (int ks = 0; ks < 8; ++ks) {
        const int j0 = 16 * ks + 8 * h;
        ar[ks][0] = *(const f16x4*)&X16[pb][l31][j0];
        ar[ks][1] = *(const f16x4*)&X16[pb][l31][j0 + 4];
        ar[ks][2] = *(const f16x4*)&X16[pb][32 + l31][j0];
        ar[ks][3] = *(const f16x4*)&X16[pb][32 + l31][j0 + 4];
      }

      // ---- (B) pack Pt into f16 pair quads (hi only)
      u32 pqh[4][4][2];
#pragma unroll
      for (int jm = 0; jm < 4; ++jm)
#pragma unroll
        for (int rq = 0; rq < 4; ++rq) {
          pqh[jm][rq][0] = pkrtz(Pacc[jm][4 * rq + 0], Pacc[jm][4 * rq + 1]);
          pqh[jm][rq][1] = pkrtz(Pacc[jm][4 * rq + 2], Pacc[jm][4 * rq + 3]);
        }

      // ---- (C) m1: acc1 = X*Pt^T  and  m1': accT = Pt*X^T (for q,y reduction)
      f32x16 accT[2];
#pragma unroll
      for (int ks = 0; ks < 8; ++ks) {
        const int a = ks >> 1, s = 2 * (ks & 1);
        f16x8 bh = bfrag(h, pqh[a][s][0], pqh[a][s][1], pqh[a][s + 1][0], pqh[a][s + 1][1]);
        f16x8 a0 = cat8(ar[ks][0], ar[ks][1]);
        f16x8 a1 = cat8(ar[ks][2], ar[ks][3]);
        if (ks == 0) {
          acc1[0] = __builtin_amdgcn_mfma_f32_32x32x16_f16(a0, bh, Z, 0, 0, 0);
          acc1[1] = __builtin_amdgcn_mfma_f32_32x32x16_f16(a1, bh, Z, 0, 0, 0);
          accT[0] = __builtin_amdgcn_mfma_f32_32x32x16_f16(bh, a0, Z, 0, 0, 0);
          accT[1] = __builtin_amdgcn_mfma_f32_32x32x16_f16(bh, a1, Z, 0, 0, 0);
        } else {
          acc1[0] = __builtin_amdgcn_mfma_f32_32x32x16_f16(a0, bh, acc1[0], 0, 0, 0);
          acc1[1] = __builtin_amdgcn_mfma_f32_32x32x16_f16(a1, bh, acc1[1], 0, 0, 0);
          accT[0] = __builtin_amdgcn_mfma_f32_32x32x16_f16(bh, a0, accT[0], 0, 0, 0);
          accT[1] = __builtin_amdgcn_mfma_f32_32x32x16_f16(bh, a1, accT[1], 0, 0, 0);
        }
      }

      // ---- (D) q = x'Ptx, y = x'theta per b: in-lane over regs (i), one
      // half-swap, one LDS write per (wave,b). accT[bt] reg r, lane(l31,h):
      // i = 32w + (r&3)+8*(r>>2)+4h, b = 32bt + l31.
      f16x4 xq[2][4];
      float4 tq[4];
#pragma unroll
      for (int rq = 0; rq < 4; ++rq) {
        const int jj = 32 * w + 8 * rq + 4 * h;
        tq[rq] = *(const float4*)&theta[jj];
        xq[0][rq] = *(const f16x4*)&X16[pb][l31][jj];
        xq[1][rq] = *(const f16x4*)&X16[pb][32 + l31][jj];
      }
#pragma unroll
      for (int bt = 0; bt < 2; ++bt) {
        float q = 0.0f, y = 0.0f;
#pragma unroll
        for (int rq = 0; rq < 4; ++rq) {
          const float* tqf = (const float*)&tq[rq];
#pragma unroll
          for (int c = 0; c < 4; ++c) {
            const float xf = (float)xq[bt][rq][c];
            q = fmaf(xf, accT[bt][4 * rq + c], q);
            y = fmaf(xf, tqf[c], y);
          }
        }
        q += sx32f(q);
        y += sx32f(y);
        if (h == 0) {
          float2 v; v.x = q; v.y = y;
          *(float2*)&pairs[w][32 * bt + l31][0] = v;
        }
      }
    } else {
      // IO: issue prefetch of x(t+1) (vmcnt stays in flight across barrier)
      if (t + 1 < T_N) XLOAD(t + 1);
    }
    wg_barrier();

    // ================= phase 2 =================
    if (wid < 4) {
      // ---- Xt-fragment prefetch for G (latency covered by E'/F below)
      f16x4 xt[4][4][2];
#pragma unroll
      for (int ks = 0; ks < 4; ++ks) {
        const int b0 = 16 * ks + 8 * h;
#pragma unroll
        for (int jm = 0; jm < 4; ++jm) {
          xt[ks][jm][0] = *(const f16x4*)&Xt16[pb][32 * jm + l31][b0];
          xt[ks][jm][1] = *(const f16x4*)&Xt16[pb][32 * jm + l31][b0 + 4];
        }
      }

      // ---- (E') per-lane b=lane: reduce pairs across P-waves, rd/err into
      // this wave's private strip (same-wave LDS is in-order: no barrier)
      {
        float qs = 0.0f, ys = 0.0f;
#pragma unroll
        for (int ww = 0; ww < 4; ++ww) {
          const float2 v = *(const float2*)&pairs[ww][lane][0];
          qs += v.x; ys += v.y;
        }
        const float rd = 1.0f / (qs + FEPS * ft);
        float2 v2; v2.x = rd; v2.y = tcur - ys;
        *(float2*)&rw[w][lane][0] = v2;
      }

      // ---- (F) K = Ptx*rd, theta update, pack km = -ft*K/B (hi only)
      const float negsc = -ft * INVB;
      u32 kq[2][4][2];
      float tsum = 0.0f;
#pragma unroll
      for (int bm = 0; bm < 2; ++bm)
#pragma unroll
        for (int rq = 0; rq < 4; ++rq) {
          const int b0 = 32 * bm + 8 * rq + 4 * h;
          const float4 q0 = *(const float4*)&rw[w][b0][0];      // rd0,e0,rd1,e1
          const float4 q1 = *(const float4*)&rw[w][b0 + 2][0];  // rd2,e2,rd3,e3
          float kr[4];
          kr[0] = acc1[bm][4 * rq + 0] * q0.x;
          kr[1] = acc1[bm][4 * rq + 1] * q0.z;
          kr[2] = acc1[bm][4 * rq + 2] * q1.x;
          kr[3] = acc1[bm][4 * rq + 3] * q1.z;
          tsum += kr[0] * q0.y + kr[1] * q0.w + kr[2] * q1.y + kr[3] * q1.w;
          kq[bm][rq][0] = pkrtz(kr[0] * negsc, kr[1] * negsc);
          kq[bm][rq][1] = pkrtz(kr[2] * negsc, kr[3] * negsc);
        }
      tsum += sx32f(tsum);
      if (h == 0) theta[i32] += tsum * INVB;  // wave-private range

      // ---- (G) m2: Pt += Xt * km  (hi only)
#pragma unroll
      for (int ks = 0; ks < 4; ++ks) {
        const int a = ks >> 1, s = 2 * (ks & 1);
        f16x8 bh = bfrag(h, kq[a][s][0], kq[a][s][1], kq[a][s + 1][0], kq[a][s + 1][1]);
#pragma unroll
        for (int jm = 0; jm < 4; ++jm) {
          f16x8 a2 = cat8(xt[ks][jm][0], xt[ks][jm][1]);
          Pacc[jm] = __builtin_amdgcn_mfma_f32_32x32x16_f16(a2, bh, Pacc[jm], 0, 0, 0);
        }
      }
      tcur = tnxt;
    } else {
      // IO wave 4: redundant ys-sum, store raw attention (overlapped with F/G)
      if (wid == 4) {
        float ys = 0.0f;
#pragma unroll
        for (int ww = 0; ww < 4; ++ww) ys += pairs[ww][lane][1];
        attn[(long)lane * T_N + t] = ys;
      }
      // IO: stage x(t+1) into the other buffer (waits vmcnt internally)
      if (t + 1 < T_N) XPREP(pb ^ 1);
    }
    wg_barrier();

    pb ^= 1;
    ft *= FF;
  }
#undef XLOAD
#undef XPREP
}

// softmax over time per batch row (in place on raw attn)
__global__ void softmax_k(float* __restrict__ attn) {
  const int b = blockIdx.x;
  float* row = attn + (long)b * T_N;
  __shared__ float sv[T_N];
  __shared__ float red[256];
  const int tid = threadIdx.x;
  float m = -1e30f;
  for (int k = tid; k < T_N; k += 256) {
    const float v = row[k];
    sv[k] = v;
    m = fmaxf(m, v);
  }
  red[tid] = m;
  __syncthreads();
  for (int off = 128; off > 0; off >>= 1) {
    if (tid < off) red[tid] = fmaxf(red[tid], red[tid + off]);
    __syncthreads();
  }
  const float M = red[0];
  __syncthreads();
  float s = 0.0f;
  for (int k = tid; k < T_N; k += 256) {
    const float e = __expf(sv[k] - M);
    sv[k] = e;
    s += e;
  }
  red[tid] = s;
  __syncthreads();
  for (int off = 128; off > 0; off >>= 1) {
    if (tid < off) red[tid] += red[tid + off];
    __syncthreads();
  }
  const float inv = 1.0f / red[0];
  for (int k = tid; k < T_N; k += 256) row[k] = sv[k] * inv;
}

// out[b][d] = sum_t x[b][t][d] * attn_norm[b][t]
__global__ void einsum_k(const float* __restrict__ xg,
                         const float* __restrict__ attn,
                         float* __restrict__ out) {
  const int b = blockIdx.x;
  const int d = threadIdx.x;  // 128 threads
  __shared__ float as[T_N];
  for (int k = d; k < T_N; k += 128) as[k] = attn[(long)b * T_N + k];
  __syncthreads();
  const float* xb = xg + (long)b * T_N * D_N + d;
  float acc = 0.0f;
#pragma unroll 4
  for (int t = 0; t < T_N; ++t) acc += xb[(long)t * D_N] * as[t];
  out[b * D_N + d] = acc;
}

extern "C" void kernel_launch(void* const* d_in, const int* in_sizes, int n_in,
                              void* d_out, int out_size, void* d_ws, size_t ws_size,
                              hipStream_t stream) {
  const float* x = (const float*)d_in[0];
  const float* tgt = (const float*)d_in[1];
  float* out = (float*)d_out;
  float* attn = out + B_N * D_N;  // outputs: [output (B,D) | attn_norm (B,T)]

  rls_seq<<<dim3(1), dim3(512), 0, stream>>>(x, tgt, attn);
  softmax_k<<<dim3(B_N), dim3(256), 0, stream>>>(attn);
  einsum_k<<<dim3(B_N), dim3(128), 0, stream>>>(x, attn, out);
}